// Round 1
// baseline (366.027 us; speedup 1.0000x reference)
//
#include <hip/hip_runtime.h>
#include <stdint.h>

#define B_ 4
#define S_ 2048
#define H_ 768
#define NH_ 12
#define HD_ 64
#define BH_ (B_ * NH_)  // 48

typedef __attribute__((ext_vector_type(4))) float f32x4;
typedef __attribute__((ext_vector_type(8))) __bf16 bf16x8;
typedef __attribute__((ext_vector_type(8))) unsigned short ushort8;

__device__ __forceinline__ unsigned short bf16rne(float f) {
  union { float f; unsigned int u; } v;
  v.f = f;
  unsigned int u = v.u;
  return (unsigned short)((u + 0x7fffu + ((u >> 16) & 1u)) >> 16);
}

__device__ __forceinline__ void gll16(const void* g, void* l) {
  __builtin_amdgcn_global_load_lds(
      (const __attribute__((address_space(1))) unsigned int*)g,
      (__attribute__((address_space(3))) unsigned int*)l, 16, 0, 0);
}

// ---------------- fp32 -> bf16 elementwise convert ----------------
__global__ __launch_bounds__(256) void cvt_bf16_kernel(const float* __restrict__ x,
                                                       unsigned short* __restrict__ y) {
  int i = (blockIdx.x * 256 + threadIdx.x) * 8;
  const float4* p = (const float4*)(x + i);
  float4 a = p[0], b = p[1];
  ushort8 r;
  r[0] = bf16rne(a.x); r[1] = bf16rne(a.y); r[2] = bf16rne(a.z); r[3] = bf16rne(a.w);
  r[4] = bf16rne(b.x); r[5] = bf16rne(b.y); r[6] = bf16rne(b.z); r[7] = bf16rne(b.w);
  *(ushort8*)(y + i) = r;
}

// ---------------- fp32 [R][C] -> bf16 transposed [C][R] ----------------
__global__ __launch_bounds__(256) void tconv_kernel(const float* __restrict__ in,
                                                    unsigned short* __restrict__ out,
                                                    int R, int C) {
  __shared__ unsigned short tile[64][72];
  int c0 = blockIdx.x * 64, r0 = blockIdx.y * 64;
  int tid = threadIdx.x;
#pragma unroll
  for (int i = 0; i < 4; ++i) {
    int c = i * 256 + tid;
    int row = c >> 4, col4 = (c & 15) * 4;
    float4 v = *(const float4*)(in + (size_t)(r0 + row) * C + c0 + col4);
    tile[row][col4 + 0] = bf16rne(v.x);
    tile[row][col4 + 1] = bf16rne(v.y);
    tile[row][col4 + 2] = bf16rne(v.z);
    tile[row][col4 + 3] = bf16rne(v.w);
  }
  __syncthreads();
#pragma unroll
  for (int i = 0; i < 2; ++i) {
    int c = i * 256 + tid;
    int oc = c >> 3, r8 = (c & 7) * 8;
    ushort8 v;
#pragma unroll
    for (int j = 0; j < 8; ++j) v[j] = tile[r8 + j][oc];
    *(ushort8*)(out + (size_t)(c0 + oc) * R + r0 + r8) = v;
  }
}

// ---------------- bf16 V [bh][S][HD] -> Vt [bh][HD][S] ----------------
__global__ __launch_bounds__(256) void vtrans_kernel(const unsigned short* __restrict__ V,
                                                     unsigned short* __restrict__ Vt) {
  __shared__ unsigned short tile[64][72];
  int t = blockIdx.x, bh = blockIdx.y, tid = threadIdx.x;
  const unsigned short* src = V + ((size_t)bh * S_ + t * 64) * HD_;
  unsigned short* dst = Vt + (size_t)bh * HD_ * S_ + t * 64;
#pragma unroll
  for (int i = 0; i < 2; ++i) {
    int c = i * 256 + tid;
    int row = c >> 3, d8 = (c & 7) * 8;
    ushort8 v = *(const ushort8*)(src + (size_t)row * HD_ + d8);
#pragma unroll
    for (int j = 0; j < 8; ++j) tile[row][d8 + j] = v[j];
  }
  __syncthreads();
#pragma unroll
  for (int i = 0; i < 2; ++i) {
    int c = i * 256 + tid;
    int d = c >> 3, s8 = (c & 7) * 8;
    ushort8 v;
#pragma unroll
    for (int j = 0; j < 8; ++j) v[j] = tile[s8 + j][d];
    *(ushort8*)(dst + (size_t)d * S_ + s8) = v;
  }
}

// ---------------- GEMM: C[M,N] = A[M,K] * B'[N,K]^T  (m97 structure) ----------------
// MODE 0: epilogue scatters bf16 into QKV [3][48][2048][64], Q scaled by 0.125
// MODE 1: epilogue stores fp32 C row-major [M][N]
template <int MODE>
__global__ __launch_bounds__(256) void gemm_bt(const unsigned short* __restrict__ A,
                                               const unsigned short* __restrict__ Bm,
                                               void* __restrict__ Cout, int N, int K) {
  __shared__ unsigned short As[128 * 32];
  __shared__ unsigned short Bs[128 * 32];
  int tid = threadIdx.x;
  int lane = tid & 63, wave = tid >> 6;
  int quad = lane >> 4, l16 = lane & 15;
  int wm = (wave & 1) * 64, wn = (wave >> 1) * 64;
  int bm = blockIdx.x, bn = blockIdx.y;
  const unsigned short* Ag = A + (size_t)bm * 128 * K;
  const unsigned short* Bg = Bm + (size_t)bn * 128 * K;

  f32x4 zero = {0.f, 0.f, 0.f, 0.f};
  f32x4 acc[4][4];
#pragma unroll
  for (int mt = 0; mt < 4; ++mt)
#pragma unroll
    for (int nt = 0; nt < 4; ++nt) acc[mt][nt] = zero;

  for (int k0 = 0; k0 < K; k0 += 32) {
#pragma unroll
    for (int i = 0; i < 2; ++i) {
      int c = i * 256 + tid;
      int row = c >> 2, off = (c & 3) * 8;
      gll16(Ag + (size_t)row * K + k0 + off, As + c * 8);
      gll16(Bg + (size_t)row * K + k0 + off, Bs + c * 8);
    }
    __syncthreads();
    bf16x8 af[4], bf[4];
#pragma unroll
    for (int mt = 0; mt < 4; ++mt)
      af[mt] = *(const bf16x8*)(As + (wm + mt * 16 + l16) * 32 + quad * 8);
#pragma unroll
    for (int nt = 0; nt < 4; ++nt)
      bf[nt] = *(const bf16x8*)(Bs + (wn + nt * 16 + l16) * 32 + quad * 8);
#pragma unroll
    for (int mt = 0; mt < 4; ++mt)
#pragma unroll
      for (int nt = 0; nt < 4; ++nt)
        acc[mt][nt] = __builtin_amdgcn_mfma_f32_16x16x32_bf16(af[mt], bf[nt], acc[mt][nt], 0, 0, 0);
    __syncthreads();
  }

  if (MODE == 0) {
    unsigned short* qkv = (unsigned short*)Cout;
#pragma unroll
    for (int mt = 0; mt < 4; ++mt)
#pragma unroll
      for (int nt = 0; nt < 4; ++nt) {
        int gn = bn * 128 + wn + nt * 16 + l16;
        int which = (gn >= 1536) ? 2 : ((gn >= 768) ? 1 : 0);
        int rem = gn - which * 768;
        int head = rem >> 6, d = rem & 63;
#pragma unroll
        for (int r = 0; r < 4; ++r) {
          int gm = bm * 128 + wm + mt * 16 + quad * 4 + r;
          int b = gm >> 11, s = gm & 2047;
          float v = acc[mt][nt][r];
          if (which == 0) v *= 0.125f;  // fold 1/sqrt(64) into Q
          qkv[(((size_t)which * BH_ + b * NH_ + head) * S_ + s) * HD_ + d] = bf16rne(v);
        }
      }
  } else {
    float* outp = (float*)Cout;
#pragma unroll
    for (int mt = 0; mt < 4; ++mt)
#pragma unroll
      for (int nt = 0; nt < 4; ++nt) {
        int gn = bn * 128 + wn + nt * 16 + l16;
#pragma unroll
        for (int r = 0; r < 4; ++r) {
          int gm = bm * 128 + wm + mt * 16 + quad * 4 + r;
          outp[(size_t)gm * N + gn] = acc[mt][nt][r];
        }
      }
  }
}

// ---------------- Flash attention, causal ----------------
// grid: (S/64, BH).  4 waves x 16 q-rows.  KV tiles of 64.
__global__ __launch_bounds__(256) void attn_kernel(const unsigned short* __restrict__ Q,
                                                   const unsigned short* __restrict__ Kg,
                                                   const unsigned short* __restrict__ Vt,
                                                   unsigned short* __restrict__ O) {
  __shared__ unsigned short Ks[64 * 64];
  __shared__ unsigned short Vs[64 * 64];   // holds V^T tile: [d][kv]
  __shared__ unsigned short Ps[4][16 * 72];
  int qt = blockIdx.x, bh = blockIdx.y;
  int tid = threadIdx.x, lane = tid & 63, wave = tid >> 6;
  int quad = lane >> 4, l16 = lane & 15;
  const unsigned short* Qp = Q + (size_t)bh * S_ * HD_;
  const unsigned short* Kp = Kg + (size_t)bh * S_ * HD_;
  const unsigned short* Vp = Vt + (size_t)bh * HD_ * S_;
  int q0 = qt * 64;
  int qrow = q0 + wave * 16 + l16;

  bf16x8 qf[2];
#pragma unroll
  for (int ks = 0; ks < 2; ++ks)
    qf[ks] = *(const bf16x8*)(Qp + (size_t)qrow * HD_ + ks * 32 + quad * 8);

  f32x4 zero = {0.f, 0.f, 0.f, 0.f};
  float m_i[4], l_i[4];
  f32x4 o[4];
#pragma unroll
  for (int r = 0; r < 4; ++r) { m_i[r] = -1e30f; l_i[r] = 0.f; }
#pragma unroll
  for (int nt = 0; nt < 4; ++nt) o[nt] = zero;

  for (int t = 0; t <= qt; ++t) {
#pragma unroll
    for (int i = 0; i < 2; ++i) {
      int c = i * 256 + tid;
      gll16(Kp + (size_t)t * 64 * HD_ + c * 8, Ks + c * 8);
      int d = c >> 3, sc = (c & 7) * 8;
      gll16(Vp + (size_t)d * S_ + t * 64 + sc, Vs + c * 8);
    }
    __syncthreads();

    // S = Q K^T  (Q pre-scaled by 0.125)
    f32x4 sf[4];
#pragma unroll
    for (int nt = 0; nt < 4; ++nt) sf[nt] = zero;
#pragma unroll
    for (int ks = 0; ks < 2; ++ks)
#pragma unroll
      for (int nt = 0; nt < 4; ++nt) {
        bf16x8 kf = *(const bf16x8*)(Ks + (nt * 16 + l16) * 64 + ks * 32 + quad * 8);
        sf[nt] = __builtin_amdgcn_mfma_f32_16x16x32_bf16(qf[ks], kf, sf[nt], 0, 0, 0);
      }

    if (t == qt) {  // causal mask on diagonal tile
#pragma unroll
      for (int nt = 0; nt < 4; ++nt)
#pragma unroll
        for (int r = 0; r < 4; ++r)
          if (nt * 16 + l16 > wave * 16 + quad * 4 + r) sf[nt][r] = -1e30f;
    }

    // online softmax
    float alpha[4], rs[4];
#pragma unroll
    for (int r = 0; r < 4; ++r) {
      float mp = fmaxf(fmaxf(sf[0][r], sf[1][r]), fmaxf(sf[2][r], sf[3][r]));
      mp = fmaxf(mp, __shfl_xor(mp, 1));
      mp = fmaxf(mp, __shfl_xor(mp, 2));
      mp = fmaxf(mp, __shfl_xor(mp, 4));
      mp = fmaxf(mp, __shfl_xor(mp, 8));
      float mn = fmaxf(m_i[r], mp);
      alpha[r] = __expf(m_i[r] - mn);
      m_i[r] = mn;
      rs[r] = 0.f;
    }
#pragma unroll
    for (int nt = 0; nt < 4; ++nt)
#pragma unroll
      for (int r = 0; r < 4; ++r) {
        float p = __expf(sf[nt][r] - m_i[r]);
        sf[nt][r] = p;
        rs[r] += p;
      }
#pragma unroll
    for (int r = 0; r < 4; ++r) {
      rs[r] += __shfl_xor(rs[r], 1);
      rs[r] += __shfl_xor(rs[r], 2);
      rs[r] += __shfl_xor(rs[r], 4);
      rs[r] += __shfl_xor(rs[r], 8);
      l_i[r] = l_i[r] * alpha[r] + rs[r];
    }
#pragma unroll
    for (int nt = 0; nt < 4; ++nt)
#pragma unroll
      for (int r = 0; r < 4; ++r) o[nt][r] *= alpha[r];

    // P: C-layout -> A-layout via per-wave LDS region
#pragma unroll
    for (int nt = 0; nt < 4; ++nt)
#pragma unroll
      for (int r = 0; r < 4; ++r)
        Ps[wave][(quad * 4 + r) * 72 + nt * 16 + l16] = bf16rne(sf[nt][r]);

    // O += P V
#pragma unroll
    for (int ks = 0; ks < 2; ++ks) {
      bf16x8 pf = *(const bf16x8*)(&Ps[wave][l16 * 72 + ks * 32 + quad * 8]);
#pragma unroll
      for (int nt = 0; nt < 4; ++nt) {
        bf16x8 vf = *(const bf16x8*)(Vs + (nt * 16 + l16) * 64 + ks * 32 + quad * 8);
        o[nt] = __builtin_amdgcn_mfma_f32_16x16x32_bf16(pf, vf, o[nt], 0, 0, 0);
      }
    }
    __syncthreads();
  }

  int b = bh / NH_, h = bh % NH_;
  float inv[4];
#pragma unroll
  for (int r = 0; r < 4; ++r) inv[r] = 1.f / l_i[r];
#pragma unroll
  for (int nt = 0; nt < 4; ++nt)
#pragma unroll
    for (int r = 0; r < 4; ++r) {
      int q = q0 + wave * 16 + quad * 4 + r;
      O[((size_t)b * S_ + q) * H_ + h * HD_ + nt * 16 + l16] = bf16rne(o[nt][r] * inv[r]);
    }
}

extern "C" void kernel_launch(void* const* d_in, const int* in_sizes, int n_in,
                              void* d_out, int out_size, void* d_ws, size_t ws_size,
                              hipStream_t stream) {
  (void)in_sizes; (void)n_in; (void)out_size; (void)ws_size;
  const float* hs = (const float*)d_in[0];
  const float* wqkv = (const float*)d_in[1];
  const float* wout = (const float*)d_in[2];
  float* out = (float*)d_out;

  unsigned short* Xbf = (unsigned short*)d_ws;                       // 8192*768
  unsigned short* Wqkvt = Xbf + (size_t)8192 * 768;                  // 2304*768
  unsigned short* Woutt = Wqkvt + (size_t)2304 * 768;                // 768*768
  unsigned short* QKV = Woutt + (size_t)768 * 768;                   // 3*48*2048*64
  unsigned short* Vt = QKV + (size_t)3 * BH_ * S_ * HD_;             // 48*64*2048
  unsigned short* Attn = Xbf;  // reuse: Xbf dead after GEMM1

  cvt_bf16_kernel<<<3072, 256, 0, stream>>>(hs, Xbf);
  tconv_kernel<<<dim3(36, 12), 256, 0, stream>>>(wqkv, Wqkvt, 768, 2304);
  tconv_kernel<<<dim3(12, 12), 256, 0, stream>>>(wout, Woutt, 768, 768);
  gemm_bt<0><<<dim3(64, 18), 256, 0, stream>>>(Xbf, Wqkvt, QKV, 2304, 768);
  vtrans_kernel<<<dim3(32, 48), 256, 0, stream>>>(QKV + (size_t)2 * BH_ * S_ * HD_, Vt);
  attn_kernel<<<dim3(32, 48), 256, 0, stream>>>(QKV, QKV + (size_t)BH_ * S_ * HD_, Vt, Attn);
  gemm_bt<1><<<dim3(64, 6), 256, 0, stream>>>(Attn, Woutt, out, 768, 768);
}

// Round 2
// 267.851 us; speedup vs baseline: 1.3665x; 1.3665x over previous
//
#include <hip/hip_runtime.h>
#include <stdint.h>

#define B_ 4
#define S_ 2048
#define H_ 768
#define NH_ 12
#define HD_ 64
#define BH_ (B_ * NH_)  // 48

typedef __attribute__((ext_vector_type(4))) float f32x4;
typedef __attribute__((ext_vector_type(8))) __bf16 bf16x8;
typedef __attribute__((ext_vector_type(8))) unsigned short ushort8;

__device__ __forceinline__ unsigned short bf16rne(float f) {
  union { float f; unsigned int u; } v;
  v.f = f;
  unsigned int u = v.u;
  return (unsigned short)((u + 0x7fffu + ((u >> 16) & 1u)) >> 16);
}

__device__ __forceinline__ void gll16(const void* g, void* l) {
  __builtin_amdgcn_global_load_lds(
      (const __attribute__((address_space(1))) unsigned int*)g,
      (__attribute__((address_space(3))) unsigned int*)l, 16, 0, 0);
}

// ---------------- fp32 -> bf16 elementwise convert ----------------
__global__ __launch_bounds__(256) void cvt_bf16_kernel(const float* __restrict__ x,
                                                       unsigned short* __restrict__ y) {
  int i = (blockIdx.x * 256 + threadIdx.x) * 8;
  const float4* p = (const float4*)(x + i);
  float4 a = p[0], b = p[1];
  ushort8 r;
  r[0] = bf16rne(a.x); r[1] = bf16rne(a.y); r[2] = bf16rne(a.z); r[3] = bf16rne(a.w);
  r[4] = bf16rne(b.x); r[5] = bf16rne(b.y); r[6] = bf16rne(b.z); r[7] = bf16rne(b.w);
  *(ushort8*)(y + i) = r;
}

// ---------------- fp32 [R][C] -> bf16 transposed [C][R] ----------------
__global__ __launch_bounds__(256) void tconv_kernel(const float* __restrict__ in,
                                                    unsigned short* __restrict__ out,
                                                    int R, int C) {
  __shared__ unsigned short tile[64][72];
  int c0 = blockIdx.x * 64, r0 = blockIdx.y * 64;
  int tid = threadIdx.x;
#pragma unroll
  for (int i = 0; i < 4; ++i) {
    int c = i * 256 + tid;
    int row = c >> 4, col4 = (c & 15) * 4;
    float4 v = *(const float4*)(in + (size_t)(r0 + row) * C + c0 + col4);
    tile[row][col4 + 0] = bf16rne(v.x);
    tile[row][col4 + 1] = bf16rne(v.y);
    tile[row][col4 + 2] = bf16rne(v.z);
    tile[row][col4 + 3] = bf16rne(v.w);
  }
  __syncthreads();
#pragma unroll
  for (int i = 0; i < 2; ++i) {
    int c = i * 256 + tid;
    int oc = c >> 3, r8 = (c & 7) * 8;
    ushort8 v;
#pragma unroll
    for (int j = 0; j < 8; ++j) v[j] = tile[r8 + j][oc];
    *(ushort8*)(out + (size_t)(c0 + oc) * R + r0 + r8) = v;
  }
}

// ---------------- bf16 V [bh][S][HD] -> Vt [bh][HD][S], XOR-swizzled ----------------
// Within each 64-col (kv) tile, 8-short blocks are placed at blk^(d&7).
__global__ __launch_bounds__(256) void vtrans_kernel(const unsigned short* __restrict__ V,
                                                     unsigned short* __restrict__ Vt) {
  __shared__ unsigned short tile[64][72];
  int t = blockIdx.x, bh = blockIdx.y, tid = threadIdx.x;
  const unsigned short* src = V + ((size_t)bh * S_ + t * 64) * HD_;
  unsigned short* dst = Vt + (size_t)bh * HD_ * S_ + t * 64;
#pragma unroll
  for (int i = 0; i < 2; ++i) {
    int c = i * 256 + tid;
    int row = c >> 3, d8 = (c & 7) * 8;
    ushort8 v = *(const ushort8*)(src + (size_t)row * HD_ + d8);
#pragma unroll
    for (int j = 0; j < 8; ++j) tile[row][d8 + j] = v[j];
  }
  __syncthreads();
#pragma unroll
  for (int i = 0; i < 2; ++i) {
    int c = i * 256 + tid;
    int d = c >> 3, sblk = c & 7;  // 8-short block along kv
    ushort8 v;
#pragma unroll
    for (int j = 0; j < 8; ++j) v[j] = tile[sblk * 8 + j][d];
    *(ushort8*)(dst + (size_t)d * S_ + (size_t)((sblk ^ (d & 7)) * 8)) = v;
  }
}

// ---------------- GEMM: C[M,N] = A[M,K] * B'[N,K]^T  (m97 structure) ----------------
// MODE 0: epilogue scatters bf16 into QKV [3][48][2048][64]; Q scaled by 0.125;
//         K rows XOR-swizzled (8-short blocks at blk^(s&7)) for conflict-free attn LDS reads.
// MODE 1: epilogue stores fp32 C row-major [M][N]
template <int MODE>
__global__ __launch_bounds__(256) void gemm_bt(const unsigned short* __restrict__ A,
                                               const unsigned short* __restrict__ Bm,
                                               void* __restrict__ Cout, int N, int K) {
  __shared__ unsigned short As[128 * 32];
  __shared__ unsigned short Bs[128 * 32];
  int tid = threadIdx.x;
  int lane = tid & 63, wave = tid >> 6;
  int quad = lane >> 4, l16 = lane & 15;
  int wm = (wave & 1) * 64, wn = (wave >> 1) * 64;
  int bm = blockIdx.x, bn = blockIdx.y;
  const unsigned short* Ag = A + (size_t)bm * 128 * K;
  const unsigned short* Bg = Bm + (size_t)bn * 128 * K;

  f32x4 zero = {0.f, 0.f, 0.f, 0.f};
  f32x4 acc[4][4];
#pragma unroll
  for (int mt = 0; mt < 4; ++mt)
#pragma unroll
    for (int nt = 0; nt < 4; ++nt) acc[mt][nt] = zero;

  for (int k0 = 0; k0 < K; k0 += 32) {
#pragma unroll
    for (int i = 0; i < 2; ++i) {
      int c = i * 256 + tid;
      int row = c >> 2, off = (c & 3) * 8;
      gll16(Ag + (size_t)row * K + k0 + off, As + c * 8);
      gll16(Bg + (size_t)row * K + k0 + off, Bs + c * 8);
    }
    __syncthreads();
    bf16x8 af[4], bf[4];
#pragma unroll
    for (int mt = 0; mt < 4; ++mt)
      af[mt] = *(const bf16x8*)(As + (wm + mt * 16 + l16) * 32 + quad * 8);
#pragma unroll
    for (int nt = 0; nt < 4; ++nt)
      bf[nt] = *(const bf16x8*)(Bs + (wn + nt * 16 + l16) * 32 + quad * 8);
#pragma unroll
    for (int mt = 0; mt < 4; ++mt)
#pragma unroll
      for (int nt = 0; nt < 4; ++nt)
        acc[mt][nt] = __builtin_amdgcn_mfma_f32_16x16x32_bf16(af[mt], bf[nt], acc[mt][nt], 0, 0, 0);
    __syncthreads();
  }

  if (MODE == 0) {
    unsigned short* qkv = (unsigned short*)Cout;
#pragma unroll
    for (int mt = 0; mt < 4; ++mt)
#pragma unroll
      for (int nt = 0; nt < 4; ++nt) {
        int gn = bn * 128 + wn + nt * 16 + l16;
        int which = (gn >= 1536) ? 2 : ((gn >= 768) ? 1 : 0);
        int rem = gn - which * 768;
        int head = rem >> 6, d = rem & 63;
#pragma unroll
        for (int r = 0; r < 4; ++r) {
          int gm = bm * 128 + wm + mt * 16 + quad * 4 + r;
          int b = gm >> 11, s = gm & 2047;
          float v = acc[mt][nt][r];
          int dd = d;
          if (which == 0) v *= 0.125f;                       // fold 1/sqrt(64) into Q
          if (which == 1) dd = (((d >> 3) ^ (s & 7)) << 3) | (d & 7);  // K swizzle
          qkv[(((size_t)which * BH_ + b * NH_ + head) * S_ + s) * HD_ + dd] = bf16rne(v);
        }
      }
  } else {
    float* outp = (float*)Cout;
#pragma unroll
    for (int mt = 0; mt < 4; ++mt)
#pragma unroll
      for (int nt = 0; nt < 4; ++nt) {
        int gn = bn * 128 + wn + nt * 16 + l16;
#pragma unroll
        for (int r = 0; r < 4; ++r) {
          int gm = bm * 128 + wm + mt * 16 + quad * 4 + r;
          outp[(size_t)gm * N + gn] = acc[mt][nt][r];
        }
      }
  }
}

// ---------------- Flash attention, causal ----------------
// grid: (BH, S/64) — qt on the SLOW axis so co-resident blocks per CU mix qts (balance).
// 4 waves x 16 q-rows.  KV tiles of 64.  K/V^T globally XOR-swizzled for bank-conflict-free
// ds_read_b128 fragment reads (blk index XOR row&7).
__global__ __launch_bounds__(256) void attn_kernel(const unsigned short* __restrict__ Q,
                                                   const unsigned short* __restrict__ Kg,
                                                   const unsigned short* __restrict__ Vt,
                                                   unsigned short* __restrict__ O) {
  __shared__ unsigned short Ks[64 * 64];
  __shared__ unsigned short Vs[64 * 64];   // V^T tile: [d][kv], kv-blocks swizzled
  __shared__ unsigned short Ps[4][16 * 72];
  int bh = blockIdx.x, qt = blockIdx.y;
  int tid = threadIdx.x, lane = tid & 63, wave = tid >> 6;
  int quad = lane >> 4, l16 = lane & 15;
  const unsigned short* Qp = Q + (size_t)bh * S_ * HD_;
  const unsigned short* Kp = Kg + (size_t)bh * S_ * HD_;
  const unsigned short* Vp = Vt + (size_t)bh * HD_ * S_;
  int q0 = qt * 64;
  int qrow = q0 + wave * 16 + l16;

  bf16x8 qf[2];
#pragma unroll
  for (int ks = 0; ks < 2; ++ks)
    qf[ks] = *(const bf16x8*)(Qp + (size_t)qrow * HD_ + ks * 32 + quad * 8);

  f32x4 zero = {0.f, 0.f, 0.f, 0.f};
  float m_i[4], l_i[4];
  f32x4 o[4];
#pragma unroll
  for (int r = 0; r < 4; ++r) { m_i[r] = -1e30f; l_i[r] = 0.f; }
#pragma unroll
  for (int nt = 0; nt < 4; ++nt) o[nt] = zero;

  for (int t = 0; t <= qt; ++t) {
#pragma unroll
    for (int i = 0; i < 2; ++i) {
      int c = i * 256 + tid;
      gll16(Kp + (size_t)t * 64 * HD_ + c * 8, Ks + c * 8);
      int d = c >> 3, sc = (c & 7) * 8;
      gll16(Vp + (size_t)d * S_ + t * 64 + sc, Vs + c * 8);
    }
    __syncthreads();

    // S = Q K^T  (Q pre-scaled by 0.125); K blocks de-swizzled on read
    f32x4 sf[4];
#pragma unroll
    for (int nt = 0; nt < 4; ++nt) sf[nt] = zero;
#pragma unroll
    for (int ks = 0; ks < 2; ++ks)
#pragma unroll
      for (int nt = 0; nt < 4; ++nt) {
        int blkx = (ks * 4 + quad) ^ (l16 & 7);
        bf16x8 kf = *(const bf16x8*)(Ks + (nt * 16 + l16) * 64 + blkx * 8);
        sf[nt] = __builtin_amdgcn_mfma_f32_16x16x32_bf16(qf[ks], kf, sf[nt], 0, 0, 0);
      }

    if (t == qt) {  // causal mask on diagonal tile
#pragma unroll
      for (int nt = 0; nt < 4; ++nt)
#pragma unroll
        for (int r = 0; r < 4; ++r)
          if (nt * 16 + l16 > wave * 16 + quad * 4 + r) sf[nt][r] = -1e30f;
    }

    // online softmax
    float alpha[4], rs[4];
#pragma unroll
    for (int r = 0; r < 4; ++r) {
      float mp = fmaxf(fmaxf(sf[0][r], sf[1][r]), fmaxf(sf[2][r], sf[3][r]));
      mp = fmaxf(mp, __shfl_xor(mp, 1));
      mp = fmaxf(mp, __shfl_xor(mp, 2));
      mp = fmaxf(mp, __shfl_xor(mp, 4));
      mp = fmaxf(mp, __shfl_xor(mp, 8));
      float mn = fmaxf(m_i[r], mp);
      alpha[r] = __expf(m_i[r] - mn);
      m_i[r] = mn;
      rs[r] = 0.f;
    }
#pragma unroll
    for (int nt = 0; nt < 4; ++nt)
#pragma unroll
      for (int r = 0; r < 4; ++r) {
        float p = __expf(sf[nt][r] - m_i[r]);
        sf[nt][r] = p;
        rs[r] += p;
      }
#pragma unroll
    for (int r = 0; r < 4; ++r) {
      rs[r] += __shfl_xor(rs[r], 1);
      rs[r] += __shfl_xor(rs[r], 2);
      rs[r] += __shfl_xor(rs[r], 4);
      rs[r] += __shfl_xor(rs[r], 8);
      l_i[r] = l_i[r] * alpha[r] + rs[r];
    }
#pragma unroll
    for (int nt = 0; nt < 4; ++nt)
#pragma unroll
      for (int r = 0; r < 4; ++r) o[nt][r] *= alpha[r];

    // P: C-layout -> A-layout via per-wave LDS region
#pragma unroll
    for (int nt = 0; nt < 4; ++nt)
#pragma unroll
      for (int r = 0; r < 4; ++r)
        Ps[wave][(quad * 4 + r) * 72 + nt * 16 + l16] = bf16rne(sf[nt][r]);

    // O += P V   (V^T rows de-swizzled on read)
#pragma unroll
    for (int ks = 0; ks < 2; ++ks) {
      bf16x8 pf = *(const bf16x8*)(&Ps[wave][l16 * 72 + ks * 32 + quad * 8]);
#pragma unroll
      for (int nt = 0; nt < 4; ++nt) {
        int blkx = (ks * 4 + quad) ^ (l16 & 7);
        bf16x8 vf = *(const bf16x8*)(Vs + (nt * 16 + l16) * 64 + blkx * 8);
        o[nt] = __builtin_amdgcn_mfma_f32_16x16x32_bf16(pf, vf, o[nt], 0, 0, 0);
      }
    }
    __syncthreads();
  }

  int b = bh / NH_, h = bh % NH_;
  float inv[4];
#pragma unroll
  for (int r = 0; r < 4; ++r) inv[r] = 1.f / l_i[r];
#pragma unroll
  for (int nt = 0; nt < 4; ++nt)
#pragma unroll
    for (int r = 0; r < 4; ++r) {
      int q = q0 + wave * 16 + quad * 4 + r;
      O[((size_t)b * S_ + q) * H_ + h * HD_ + nt * 16 + l16] = bf16rne(o[nt][r] * inv[r]);
    }
}

extern "C" void kernel_launch(void* const* d_in, const int* in_sizes, int n_in,
                              void* d_out, int out_size, void* d_ws, size_t ws_size,
                              hipStream_t stream) {
  (void)in_sizes; (void)n_in; (void)out_size; (void)ws_size;
  const float* hs = (const float*)d_in[0];
  const float* wqkv = (const float*)d_in[1];
  const float* wout = (const float*)d_in[2];
  float* out = (float*)d_out;

  unsigned short* Xbf = (unsigned short*)d_ws;                       // 8192*768
  unsigned short* Wqkvt = Xbf + (size_t)8192 * 768;                  // 2304*768
  unsigned short* Woutt = Wqkvt + (size_t)2304 * 768;                // 768*768
  unsigned short* QKV = Woutt + (size_t)768 * 768;                   // 3*48*2048*64
  unsigned short* Vt = QKV + (size_t)3 * BH_ * S_ * HD_;             // 48*64*2048
  unsigned short* Attn = Xbf;  // reuse: Xbf dead after GEMM1

  cvt_bf16_kernel<<<3072, 256, 0, stream>>>(hs, Xbf);
  tconv_kernel<<<dim3(36, 12), 256, 0, stream>>>(wqkv, Wqkvt, 768, 2304);
  tconv_kernel<<<dim3(12, 12), 256, 0, stream>>>(wout, Woutt, 768, 768);
  gemm_bt<0><<<dim3(64, 18), 256, 0, stream>>>(Xbf, Wqkvt, QKV, 2304, 768);
  vtrans_kernel<<<dim3(32, 48), 256, 0, stream>>>(QKV + (size_t)2 * BH_ * S_ * HD_, Vt);
  attn_kernel<<<dim3(48, 32), 256, 0, stream>>>(QKV, QKV + (size_t)BH_ * S_ * HD_, Vt, Attn);
  gemm_bt<1><<<dim3(64, 6), 256, 0, stream>>>(Attn, Woutt, out, 768, 768);
}

// Round 3
// 250.115 us; speedup vs baseline: 1.4634x; 1.0709x over previous
//
#include <hip/hip_runtime.h>
#include <stdint.h>

#define B_ 4
#define S_ 2048
#define H_ 768
#define NH_ 12
#define HD_ 64
#define BH_ (B_ * NH_)  // 48

typedef __attribute__((ext_vector_type(4))) float f32x4;
typedef __attribute__((ext_vector_type(8))) __bf16 bf16x8;
typedef __attribute__((ext_vector_type(8))) unsigned short ushort8;

__device__ __forceinline__ unsigned short bf16rne(float f) {
  union { float f; unsigned int u; } v;
  v.f = f;
  unsigned int u = v.u;
  return (unsigned short)((u + 0x7fffu + ((u >> 16) & 1u)) >> 16);
}

__device__ __forceinline__ void gll16(const void* g, void* l) {
  __builtin_amdgcn_global_load_lds(
      (const __attribute__((address_space(1))) unsigned int*)g,
      (__attribute__((address_space(3))) unsigned int*)l, 16, 0, 0);
}

// ---------------- fp32 -> bf16 elementwise convert ----------------
__global__ __launch_bounds__(256) void cvt_bf16_kernel(const float* __restrict__ x,
                                                       unsigned short* __restrict__ y) {
  int i = (blockIdx.x * 256 + threadIdx.x) * 8;
  const float4* p = (const float4*)(x + i);
  float4 a = p[0], b = p[1];
  ushort8 r;
  r[0] = bf16rne(a.x); r[1] = bf16rne(a.y); r[2] = bf16rne(a.z); r[3] = bf16rne(a.w);
  r[4] = bf16rne(b.x); r[5] = bf16rne(b.y); r[6] = bf16rne(b.z); r[7] = bf16rne(b.w);
  *(ushort8*)(y + i) = r;
}

// ---------------- fp32 [R][C] -> bf16 transposed [C][R] ----------------
__global__ __launch_bounds__(256) void tconv_kernel(const float* __restrict__ in,
                                                    unsigned short* __restrict__ out,
                                                    int R, int C) {
  __shared__ unsigned short tile[64][72];
  int c0 = blockIdx.x * 64, r0 = blockIdx.y * 64;
  int tid = threadIdx.x;
#pragma unroll
  for (int i = 0; i < 4; ++i) {
    int c = i * 256 + tid;
    int row = c >> 4, col4 = (c & 15) * 4;
    float4 v = *(const float4*)(in + (size_t)(r0 + row) * C + c0 + col4);
    tile[row][col4 + 0] = bf16rne(v.x);
    tile[row][col4 + 1] = bf16rne(v.y);
    tile[row][col4 + 2] = bf16rne(v.z);
    tile[row][col4 + 3] = bf16rne(v.w);
  }
  __syncthreads();
#pragma unroll
  for (int i = 0; i < 2; ++i) {
    int c = i * 256 + tid;
    int oc = c >> 3, r8 = (c & 7) * 8;
    ushort8 v;
#pragma unroll
    for (int j = 0; j < 8; ++j) v[j] = tile[r8 + j][oc];
    *(ushort8*)(out + (size_t)(c0 + oc) * R + r0 + r8) = v;
  }
}

// ---------------- bf16 V [bh][S][HD] -> Vt [bh][HD][S], XOR-swizzled ----------------
// Within each 64-col (kv) tile, 8-short blocks are placed at blk^(d&7).
__global__ __launch_bounds__(256) void vtrans_kernel(const unsigned short* __restrict__ V,
                                                     unsigned short* __restrict__ Vt) {
  __shared__ unsigned short tile[64][72];
  int t = blockIdx.x, bh = blockIdx.y, tid = threadIdx.x;
  const unsigned short* src = V + ((size_t)bh * S_ + t * 64) * HD_;
  unsigned short* dst = Vt + (size_t)bh * HD_ * S_ + t * 64;
#pragma unroll
  for (int i = 0; i < 2; ++i) {
    int c = i * 256 + tid;
    int row = c >> 3, d8 = (c & 7) * 8;
    ushort8 v = *(const ushort8*)(src + (size_t)row * HD_ + d8);
#pragma unroll
    for (int j = 0; j < 8; ++j) tile[row][d8 + j] = v[j];
  }
  __syncthreads();
#pragma unroll
  for (int i = 0; i < 2; ++i) {
    int c = i * 256 + tid;
    int d = c >> 3, sblk = c & 7;  // 8-short block along kv
    ushort8 v;
#pragma unroll
    for (int j = 0; j < 8; ++j) v[j] = tile[sblk * 8 + j][d];
    *(ushort8*)(dst + (size_t)d * S_ + (size_t)((sblk ^ (d & 7)) * 8)) = v;
  }
}

// ---------------- GEMM: C[M,N] = A[M,K] * B'[N,K]^T  (m97 structure) ----------------
// MODE 0: epilogue scatters bf16 into QKV [3][48][2048][64]; Q scaled by 0.125;
//         K rows XOR-swizzled (8-short blocks at blk^(s&7)) for conflict-free attn LDS reads.
// MODE 1: epilogue stores fp32 C row-major [M][N]
template <int MODE>
__global__ __launch_bounds__(256) void gemm_bt(const unsigned short* __restrict__ A,
                                               const unsigned short* __restrict__ Bm,
                                               void* __restrict__ Cout, int N, int K) {
  __shared__ unsigned short As[128 * 32];
  __shared__ unsigned short Bs[128 * 32];
  int tid = threadIdx.x;
  int lane = tid & 63, wave = tid >> 6;
  int quad = lane >> 4, l16 = lane & 15;
  int wm = (wave & 1) * 64, wn = (wave >> 1) * 64;
  int bm = blockIdx.x, bn = blockIdx.y;
  const unsigned short* Ag = A + (size_t)bm * 128 * K;
  const unsigned short* Bg = Bm + (size_t)bn * 128 * K;

  f32x4 zero = {0.f, 0.f, 0.f, 0.f};
  f32x4 acc[4][4];
#pragma unroll
  for (int mt = 0; mt < 4; ++mt)
#pragma unroll
    for (int nt = 0; nt < 4; ++nt) acc[mt][nt] = zero;

  for (int k0 = 0; k0 < K; k0 += 32) {
#pragma unroll
    for (int i = 0; i < 2; ++i) {
      int c = i * 256 + tid;
      int row = c >> 2, off = (c & 3) * 8;
      gll16(Ag + (size_t)row * K + k0 + off, As + c * 8);
      gll16(Bg + (size_t)row * K + k0 + off, Bs + c * 8);
    }
    __syncthreads();
    bf16x8 af[4], bf[4];
#pragma unroll
    for (int mt = 0; mt < 4; ++mt)
      af[mt] = *(const bf16x8*)(As + (wm + mt * 16 + l16) * 32 + quad * 8);
#pragma unroll
    for (int nt = 0; nt < 4; ++nt)
      bf[nt] = *(const bf16x8*)(Bs + (wn + nt * 16 + l16) * 32 + quad * 8);
#pragma unroll
    for (int mt = 0; mt < 4; ++mt)
#pragma unroll
      for (int nt = 0; nt < 4; ++nt)
        acc[mt][nt] = __builtin_amdgcn_mfma_f32_16x16x32_bf16(af[mt], bf[nt], acc[mt][nt], 0, 0, 0);
    __syncthreads();
  }

  if (MODE == 0) {
    unsigned short* qkv = (unsigned short*)Cout;
#pragma unroll
    for (int mt = 0; mt < 4; ++mt)
#pragma unroll
      for (int nt = 0; nt < 4; ++nt) {
        int gn = bn * 128 + wn + nt * 16 + l16;
        int which = (gn >= 1536) ? 2 : ((gn >= 768) ? 1 : 0);
        int rem = gn - which * 768;
        int head = rem >> 6, d = rem & 63;
#pragma unroll
        for (int r = 0; r < 4; ++r) {
          int gm = bm * 128 + wm + mt * 16 + quad * 4 + r;
          int b = gm >> 11, s = gm & 2047;
          float v = acc[mt][nt][r];
          int dd = d;
          if (which == 0) v *= 0.125f;                       // fold 1/sqrt(64) into Q
          if (which == 1) dd = (((d >> 3) ^ (s & 7)) << 3) | (d & 7);  // K swizzle
          qkv[(((size_t)which * BH_ + b * NH_ + head) * S_ + s) * HD_ + dd] = bf16rne(v);
        }
      }
  } else {
    float* outp = (float*)Cout;
#pragma unroll
    for (int mt = 0; mt < 4; ++mt)
#pragma unroll
      for (int nt = 0; nt < 4; ++nt) {
        int gn = bn * 128 + wn + nt * 16 + l16;
#pragma unroll
        for (int r = 0; r < 4; ++r) {
          int gm = bm * 128 + wm + mt * 16 + quad * 4 + r;
          outp[(size_t)gm * N + gn] = acc[mt][nt][r];
        }
      }
  }
}

// ---------------- Flash attention, causal ----------------
// grid: (BH, S/64) — qt slow for per-CU balance.  4 waves x 16 q-rows, KV tiles of 64.
// Double-buffered K/V staging, ONE barrier per iter: prefetch t+1 right after the
// barrier, compute on t, next iter's barrier drains the prefetch (latency hidden).
// K/V^T globally XOR-swizzled; Ps XOR-swizzled at stride 64.  Row-sum of P via
// MFMA-with-ones (matrix pipe) instead of 16 cross-lane shuffles.
__global__ __launch_bounds__(256) void attn_kernel(const unsigned short* __restrict__ Q,
                                                   const unsigned short* __restrict__ Kg,
                                                   const unsigned short* __restrict__ Vt,
                                                   unsigned short* __restrict__ O) {
  __shared__ unsigned short Ks[2][64 * 64];
  __shared__ unsigned short Vs[2][64 * 64];   // V^T tile: [d][kv], kv-blocks swizzled
  __shared__ unsigned short Ps[4][16 * 64];   // per-wave P, XOR-swizzled, stride 64
  int bh = blockIdx.x, qt = blockIdx.y;
  int tid = threadIdx.x, lane = tid & 63, wave = tid >> 6;
  int quad = lane >> 4, l16 = lane & 15;
  const unsigned short* Qp = Q + (size_t)bh * S_ * HD_;
  const unsigned short* Kp = Kg + (size_t)bh * S_ * HD_;
  const unsigned short* Vp = Vt + (size_t)bh * HD_ * S_;
  int q0 = qt * 64;
  int qrow = q0 + wave * 16 + l16;

  auto stage = [&](int t, int buf) {
#pragma unroll
    for (int i = 0; i < 2; ++i) {
      int c = i * 256 + tid;
      gll16(Kp + (size_t)t * 64 * HD_ + c * 8, &Ks[buf][c * 8]);
      int d = c >> 3, sc = (c & 7) * 8;
      gll16(Vp + (size_t)d * S_ + t * 64 + sc, &Vs[buf][c * 8]);
    }
  };

  stage(0, 0);  // prefetch first tile; Q-frag loads below overlap its latency

  bf16x8 qf[2];
#pragma unroll
  for (int ks = 0; ks < 2; ++ks)
    qf[ks] = *(const bf16x8*)(Qp + (size_t)qrow * HD_ + ks * 32 + quad * 8);

  bf16x8 ones;
#pragma unroll
  for (int j = 0; j < 8; ++j) ones[j] = (__bf16)1.0f;

  f32x4 zero = {0.f, 0.f, 0.f, 0.f};
  float m_i[4], l_i[4];
  f32x4 o[4];
#pragma unroll
  for (int r = 0; r < 4; ++r) { m_i[r] = -1e30f; l_i[r] = 0.f; }
#pragma unroll
  for (int nt = 0; nt < 4; ++nt) o[nt] = zero;

  for (int t = 0; t <= qt; ++t) {
    __syncthreads();                    // drains prefetch(t) + guards buffer reuse
    if (t < qt) stage(t + 1, (t + 1) & 1);  // async prefetch overlaps compute below
    const unsigned short* Kb = Ks[t & 1];
    const unsigned short* Vb = Vs[t & 1];

    // S = Q K^T  (Q pre-scaled by 0.125); K blocks de-swizzled on read
    f32x4 sf[4];
#pragma unroll
    for (int nt = 0; nt < 4; ++nt) sf[nt] = zero;
#pragma unroll
    for (int ks = 0; ks < 2; ++ks)
#pragma unroll
      for (int nt = 0; nt < 4; ++nt) {
        int blkx = (ks * 4 + quad) ^ (l16 & 7);
        bf16x8 kf = *(const bf16x8*)(Kb + (nt * 16 + l16) * 64 + blkx * 8);
        sf[nt] = __builtin_amdgcn_mfma_f32_16x16x32_bf16(qf[ks], kf, sf[nt], 0, 0, 0);
      }

    if (t == qt) {  // causal mask on diagonal tile
#pragma unroll
      for (int nt = 0; nt < 4; ++nt)
#pragma unroll
        for (int r = 0; r < 4; ++r)
          if (nt * 16 + l16 > wave * 16 + quad * 4 + r) sf[nt][r] = -1e30f;
    }

    // online softmax: row-max via 16-lane shuffles, row-sum via MFMA below
    float alpha[4];
#pragma unroll
    for (int r = 0; r < 4; ++r) {
      float mp = fmaxf(fmaxf(sf[0][r], sf[1][r]), fmaxf(sf[2][r], sf[3][r]));
      mp = fmaxf(mp, __shfl_xor(mp, 1));
      mp = fmaxf(mp, __shfl_xor(mp, 2));
      mp = fmaxf(mp, __shfl_xor(mp, 4));
      mp = fmaxf(mp, __shfl_xor(mp, 8));
      float mn = fmaxf(m_i[r], mp);
      alpha[r] = __expf(m_i[r] - mn);
      m_i[r] = mn;
    }
#pragma unroll
    for (int nt = 0; nt < 4; ++nt)
#pragma unroll
      for (int r = 0; r < 4; ++r) {
        float p = __expf(sf[nt][r] - m_i[r]);
        // P write: C-layout (row=quad*4+r, col=nt*16+l16) -> A-layout region, swizzled
        int row = quad * 4 + r;
        int colblk = nt * 2 + (l16 >> 3);
        Ps[wave][row * 64 + ((colblk ^ (row & 7)) << 3) + (l16 & 7)] = bf16rne(p);
      }
#pragma unroll
    for (int nt = 0; nt < 4; ++nt)
#pragma unroll
      for (int r = 0; r < 4; ++r) o[nt][r] *= alpha[r];

    // O += P V ;  rowsum(P) via MFMA with ones (exact, on matrix pipe)
    f32x4 rsv = zero;
#pragma unroll
    for (int ks = 0; ks < 2; ++ks) {
      int swkb = (ks * 4 + quad) ^ (l16 & 7);
      bf16x8 pf = *(const bf16x8*)(&Ps[wave][l16 * 64 + swkb * 8]);
      rsv = __builtin_amdgcn_mfma_f32_16x16x32_bf16(pf, ones, rsv, 0, 0, 0);
#pragma unroll
      for (int nt = 0; nt < 4; ++nt) {
        int blkx = (ks * 4 + quad) ^ (l16 & 7);
        bf16x8 vf = *(const bf16x8*)(Vb + (nt * 16 + l16) * 64 + blkx * 8);
        o[nt] = __builtin_amdgcn_mfma_f32_16x16x32_bf16(pf, vf, o[nt], 0, 0, 0);
      }
    }
#pragma unroll
    for (int r = 0; r < 4; ++r) l_i[r] = l_i[r] * alpha[r] + rsv[r];
  }

  int b = bh / NH_, h = bh % NH_;
  float inv[4];
#pragma unroll
  for (int r = 0; r < 4; ++r) inv[r] = 1.f / l_i[r];
#pragma unroll
  for (int nt = 0; nt < 4; ++nt)
#pragma unroll
    for (int r = 0; r < 4; ++r) {
      int q = q0 + wave * 16 + quad * 4 + r;
      O[((size_t)b * S_ + q) * H_ + h * HD_ + nt * 16 + l16] = bf16rne(o[nt][r] * inv[r]);
    }
}

extern "C" void kernel_launch(void* const* d_in, const int* in_sizes, int n_in,
                              void* d_out, int out_size, void* d_ws, size_t ws_size,
                              hipStream_t stream) {
  (void)in_sizes; (void)n_in; (void)out_size; (void)ws_size;
  const float* hs = (const float*)d_in[0];
  const float* wqkv = (const float*)d_in[1];
  const float* wout = (const float*)d_in[2];
  float* out = (float*)d_out;

  unsigned short* Xbf = (unsigned short*)d_ws;                       // 8192*768
  unsigned short* Wqkvt = Xbf + (size_t)8192 * 768;                  // 2304*768
  unsigned short* Woutt = Wqkvt + (size_t)2304 * 768;                // 768*768
  unsigned short* QKV = Woutt + (size_t)768 * 768;                   // 3*48*2048*64
  unsigned short* Vt = QKV + (size_t)3 * BH_ * S_ * HD_;             // 48*64*2048
  unsigned short* Attn = Xbf;  // reuse: Xbf dead after GEMM1

  cvt_bf16_kernel<<<3072, 256, 0, stream>>>(hs, Xbf);
  tconv_kernel<<<dim3(36, 12), 256, 0, stream>>>(wqkv, Wqkvt, 768, 2304);
  tconv_kernel<<<dim3(12, 12), 256, 0, stream>>>(wout, Woutt, 768, 768);
  gemm_bt<0><<<dim3(64, 18), 256, 0, stream>>>(Xbf, Wqkvt, QKV, 2304, 768);
  vtrans_kernel<<<dim3(32, 48), 256, 0, stream>>>(QKV + (size_t)2 * BH_ * S_ * HD_, Vt);
  attn_kernel<<<dim3(48, 32), 256, 0, stream>>>(QKV, QKV + (size_t)BH_ * S_ * HD_, Vt, Attn);
  gemm_bt<1><<<dim3(64, 6), 256, 0, stream>>>(Attn, Woutt, out, 768, 768);
}

// Round 4
// 225.221 us; speedup vs baseline: 1.6252x; 1.1105x over previous
//
#include <hip/hip_runtime.h>
#include <stdint.h>

#define B_ 4
#define S_ 2048
#define H_ 768
#define NH_ 12
#define HD_ 64
#define BH_ (B_ * NH_)  // 48

typedef __attribute__((ext_vector_type(4))) float f32x4;
typedef __attribute__((ext_vector_type(8))) __bf16 bf16x8;
typedef __attribute__((ext_vector_type(8))) unsigned short ushort8;
typedef __attribute__((ext_vector_type(4))) unsigned short ushort4v;

__device__ __forceinline__ unsigned short bf16rne(float f) {
  union { float f; unsigned int u; } v;
  v.f = f;
  unsigned int u = v.u;
  return (unsigned short)((u + 0x7fffu + ((u >> 16) & 1u)) >> 16);
}

__device__ __forceinline__ void gll16(const void* g, void* l) {
  __builtin_amdgcn_global_load_lds(
      (const __attribute__((address_space(1))) unsigned int*)g,
      (__attribute__((address_space(3))) unsigned int*)l, 16, 0, 0);
}

// ---------------- fp32 -> bf16 elementwise convert ----------------
__global__ __launch_bounds__(256) void cvt_bf16_kernel(const float* __restrict__ x,
                                                       unsigned short* __restrict__ y) {
  int i = (blockIdx.x * 256 + threadIdx.x) * 8;
  const float4* p = (const float4*)(x + i);
  float4 a = p[0], b = p[1];
  ushort8 r;
  r[0] = bf16rne(a.x); r[1] = bf16rne(a.y); r[2] = bf16rne(a.z); r[3] = bf16rne(a.w);
  r[4] = bf16rne(b.x); r[5] = bf16rne(b.y); r[6] = bf16rne(b.z); r[7] = bf16rne(b.w);
  *(ushort8*)(y + i) = r;
}

// ---------------- fp32 [R][C] -> bf16 transposed [C][R] ----------------
__global__ __launch_bounds__(256) void tconv_kernel(const float* __restrict__ in,
                                                    unsigned short* __restrict__ out,
                                                    int R, int C) {
  __shared__ unsigned short tile[64][72];
  int c0 = blockIdx.x * 64, r0 = blockIdx.y * 64;
  int tid = threadIdx.x;
#pragma unroll
  for (int i = 0; i < 4; ++i) {
    int c = i * 256 + tid;
    int row = c >> 4, col4 = (c & 15) * 4;
    float4 v = *(const float4*)(in + (size_t)(r0 + row) * C + c0 + col4);
    tile[row][col4 + 0] = bf16rne(v.x);
    tile[row][col4 + 1] = bf16rne(v.y);
    tile[row][col4 + 2] = bf16rne(v.z);
    tile[row][col4 + 3] = bf16rne(v.w);
  }
  __syncthreads();
#pragma unroll
  for (int i = 0; i < 2; ++i) {
    int c = i * 256 + tid;
    int oc = c >> 3, r8 = (c & 7) * 8;
    ushort8 v;
#pragma unroll
    for (int j = 0; j < 8; ++j) v[j] = tile[r8 + j][oc];
    *(ushort8*)(out + (size_t)(c0 + oc) * R + r0 + r8) = v;
  }
}

// ---------------- GEMM: 128x128 tile, A[M,K] * B'[N,K]^T  (m97 structure) ----------------
// MODE 0: QK blocks (bn<12): swapped mfma (C^T tile) -> r-axis = feature -> b64 stores
//         into Q [bh][s][d] (x0.125) and K [bh][s][d] (d-blocks XOR-swizzled by s&7).
// MODE 2: V blocks: normal mfma -> r-axis = token -> b64 stores into Vt [bh][d][s]
//         (s-blocks XOR-swizzled by d&7).  Cout = Vt base.
// MODE 1: fp32 out: swapped mfma -> float4 stores row-major [M][N].
template <int MODE>
__global__ __launch_bounds__(256) void gemm_bt(const unsigned short* __restrict__ A,
                                               const unsigned short* __restrict__ Bm,
                                               void* __restrict__ Cout, int N, int K,
                                               int bn_off) {
  __shared__ unsigned short As[128 * 32];
  __shared__ unsigned short Bs[128 * 32];
  int tid = threadIdx.x;
  int lane = tid & 63, wave = tid >> 6;
  int quad = lane >> 4, l16 = lane & 15;
  int wm = (wave & 1) * 64, wn = (wave >> 1) * 64;
  int bm = blockIdx.x, bn = blockIdx.y + bn_off;
  const unsigned short* Ag = A + (size_t)bm * 128 * K;
  const unsigned short* Bg = Bm + (size_t)bn * 128 * K;

  f32x4 zero = {0.f, 0.f, 0.f, 0.f};
  f32x4 acc[4][4];
#pragma unroll
  for (int mt = 0; mt < 4; ++mt)
#pragma unroll
    for (int nt = 0; nt < 4; ++nt) acc[mt][nt] = zero;

  for (int k0 = 0; k0 < K; k0 += 32) {
#pragma unroll
    for (int i = 0; i < 2; ++i) {
      int c = i * 256 + tid;
      int row = c >> 2, off = (c & 3) * 8;
      gll16(Ag + (size_t)row * K + k0 + off, As + c * 8);
      gll16(Bg + (size_t)row * K + k0 + off, Bs + c * 8);
    }
    __syncthreads();
    bf16x8 af[4], bf[4];
#pragma unroll
    for (int mt = 0; mt < 4; ++mt)
      af[mt] = *(const bf16x8*)(As + (wm + mt * 16 + l16) * 32 + quad * 8);
#pragma unroll
    for (int nt = 0; nt < 4; ++nt)
      bf[nt] = *(const bf16x8*)(Bs + (wn + nt * 16 + l16) * 32 + quad * 8);
#pragma unroll
    for (int mt = 0; mt < 4; ++mt)
#pragma unroll
      for (int nt = 0; nt < 4; ++nt) {
        if (MODE == 2)
          acc[mt][nt] = __builtin_amdgcn_mfma_f32_16x16x32_bf16(af[mt], bf[nt], acc[mt][nt], 0, 0, 0);
        else  // transposed: rows = features (b-side), cols = tokens (a-side)
          acc[mt][nt] = __builtin_amdgcn_mfma_f32_16x16x32_bf16(bf[nt], af[mt], acc[mt][nt], 0, 0, 0);
      }
    __syncthreads();
  }

  if (MODE == 0) {
    unsigned short* qkv = (unsigned short*)Cout;
    int which = (bn >= 6);  // block-uniform: bn 0..5 = Q, 6..11 = K
#pragma unroll
    for (int mt = 0; mt < 4; ++mt)
#pragma unroll
      for (int nt = 0; nt < 4; ++nt) {
        int f0 = bn * 128 + wn + nt * 16 + quad * 4;  // feature base (r contiguous)
        int tm = bm * 128 + wm + mt * 16 + l16;       // token
        int rem = f0 - which * 768;
        int head = rem >> 6, d0 = rem & 63;
        int b = tm >> 11, s = tm & 2047;
        ushort4v pk;
        if (which == 0) {
#pragma unroll
          for (int r = 0; r < 4; ++r) pk[r] = bf16rne(acc[mt][nt][r] * 0.125f);
          *(ushort4v*)(qkv + (((size_t)b * NH_ + head) * S_ + s) * HD_ + d0) = pk;
        } else {
#pragma unroll
          for (int r = 0; r < 4; ++r) pk[r] = bf16rne(acc[mt][nt][r]);
          int dd0 = (((d0 >> 3) ^ (s & 7)) << 3) | (d0 & 7);
          *(ushort4v*)(qkv + (((size_t)(BH_ + b * NH_ + head)) * S_ + s) * HD_ + dd0) = pk;
        }
      }
  } else if (MODE == 2) {
    unsigned short* vt = (unsigned short*)Cout;
#pragma unroll
    for (int mt = 0; mt < 4; ++mt)
#pragma unroll
      for (int nt = 0; nt < 4; ++nt) {
        int f = bn * 128 + wn + nt * 16 + l16;        // feature (lane)
        int t0 = bm * 128 + wm + mt * 16 + quad * 4;  // token base (r contiguous)
        int rem = f - 1536;
        int head = rem >> 6, d = rem & 63;
        int b = t0 >> 11, s0 = t0 & 2047;
        int tile = s0 >> 6, sin = s0 & 63;
        int pos = (((sin >> 3) ^ (d & 7)) << 3) | (sin & 7);
        ushort4v pk;
#pragma unroll
        for (int r = 0; r < 4; ++r) pk[r] = bf16rne(acc[mt][nt][r]);
        *(ushort4v*)(vt + (((size_t)(b * NH_ + head)) * HD_ + d) * S_ + tile * 64 + pos) = pk;
      }
  } else {
    float* outp = (float*)Cout;
#pragma unroll
    for (int mt = 0; mt < 4; ++mt)
#pragma unroll
      for (int nt = 0; nt < 4; ++nt) {
        int f0 = bn * 128 + wn + nt * 16 + quad * 4;
        int tm = bm * 128 + wm + mt * 16 + l16;
        *(f32x4*)(outp + (size_t)tm * N + f0) = acc[mt][nt];
      }
  }
}

// ---------------- Flash attention, causal, S^T formulation ----------------
// grid (48, 16): 512 threads, Q-tile 128 (8 waves x 16 q), KV tiles 64, dbuf K/V.
// S^T = K·Q  => softmax state is per-lane scalar (q = l16 column).
// P^T->LDS via 4x ds_write_b64; O^T = V^T·P^T => packed b64 O stores.
// qt interleave map (0,15,1,14,...) balances per-CU work at 3 blocks/CU.
__global__ __launch_bounds__(512, 6) void attn_kernel(const unsigned short* __restrict__ Q,
                                                      const unsigned short* __restrict__ Kg,
                                                      const unsigned short* __restrict__ Vt,
                                                      unsigned short* __restrict__ O) {
  __shared__ unsigned short Ks[2][64 * 64];
  __shared__ unsigned short Vs[2][64 * 64];
  __shared__ unsigned short Ps[8][16 * 64];
  int bh = blockIdx.x;
  int y = blockIdx.y;
  int qt = (y & 1) ? (15 - (y >> 1)) : (y >> 1);
  int tid = threadIdx.x, lane = tid & 63, wave = tid >> 6;
  int quad = lane >> 4, l16 = lane & 15;
  const unsigned short* Qp = Q + (size_t)bh * S_ * HD_;
  const unsigned short* Kp = Kg + (size_t)bh * S_ * HD_;
  const unsigned short* Vp = Vt + (size_t)bh * HD_ * S_;
  int q0 = qt * 128;
  int qrow = q0 + wave * 16 + l16;                 // this lane's q (S^T column)
  int kmax_w = (q0 + wave * 16 + 15) >> 6;         // last kv-tile this wave needs
  int kmax_b = 2 * qt + 1;                         // last kv-tile this block stages

  auto stage = [&](int t, int buf) {               // 512 thr: 1 gll16 each for K and V
    int row = tid >> 3, off = (tid & 7) * 8;
    gll16(Kp + (size_t)t * 64 * HD_ + row * HD_ + off, &Ks[buf][tid * 8]);
    gll16(Vp + (size_t)row * S_ + t * 64 + off, &Vs[buf][tid * 8]);
  };

  stage(0, 0);  // Q-frag loads below overlap the first staging

  bf16x8 qf[2];
#pragma unroll
  for (int ks = 0; ks < 2; ++ks)
    qf[ks] = *(const bf16x8*)(Qp + (size_t)qrow * HD_ + ks * 32 + quad * 8);

  bf16x8 ones;
#pragma unroll
  for (int j = 0; j < 8; ++j) ones[j] = (__bf16)1.0f;

  f32x4 zero = {0.f, 0.f, 0.f, 0.f};
  float m_i = -1e30f, l_i = 0.f;
  f32x4 o[4];
#pragma unroll
  for (int nt = 0; nt < 4; ++nt) o[nt] = zero;

  for (int t = 0; t <= kmax_b; ++t) {
    __syncthreads();                       // drains prefetch(t) + guards buffer reuse
    if (t < kmax_b) stage(t + 1, (t + 1) & 1);
    if (t > kmax_w) continue;              // fully-masked tile for this wave
    const unsigned short* Kb = Ks[t & 1];
    const unsigned short* Vb = Vs[t & 1];

    // S^T = K·Q : rows kv (quad*4+r per nt-block), cols q (l16)
    f32x4 sf[4];
#pragma unroll
    for (int nt = 0; nt < 4; ++nt) sf[nt] = zero;
#pragma unroll
    for (int ks = 0; ks < 2; ++ks)
#pragma unroll
      for (int nt = 0; nt < 4; ++nt) {
        bf16x8 kf = *(const bf16x8*)(Kb + (nt * 16 + l16) * 64 + (((ks * 4 + quad) ^ (l16 & 7)) << 3));
        sf[nt] = __builtin_amdgcn_mfma_f32_16x16x32_bf16(kf, qf[ks], sf[nt], 0, 0, 0);
      }

    if (t == kmax_w) {  // causal boundary tile: mask kv > q
#pragma unroll
      for (int nt = 0; nt < 4; ++nt)
#pragma unroll
        for (int r = 0; r < 4; ++r)
          if (t * 64 + nt * 16 + quad * 4 + r > qrow) sf[nt][r] = -1e30f;
    }

    // per-lane scalar online softmax (column q = l16)
    float mx = fmaxf(fmaxf(fmaxf(sf[0][0], sf[0][1]), fmaxf(sf[0][2], sf[0][3])),
                     fmaxf(fmaxf(sf[1][0], sf[1][1]), fmaxf(sf[1][2], sf[1][3])));
    mx = fmaxf(mx, fmaxf(fmaxf(fmaxf(sf[2][0], sf[2][1]), fmaxf(sf[2][2], sf[2][3])),
                         fmaxf(fmaxf(sf[3][0], sf[3][1]), fmaxf(sf[3][2], sf[3][3]))));
    mx = fmaxf(mx, __shfl_xor(mx, 16));
    mx = fmaxf(mx, __shfl_xor(mx, 32));
    float mn = fmaxf(m_i, mx);
    float alpha = __expf(m_i - mn);
    m_i = mn;

    // P^T -> Ps[q][kv] (A/B-frag readable), XOR-swizzled 8-blocks, b64 writes
#pragma unroll
    for (int nt = 0; nt < 4; ++nt) {
      ushort4v pk;
#pragma unroll
      for (int r = 0; r < 4; ++r) pk[r] = bf16rne(__expf(sf[nt][r] - mn));
      int kvblk = nt * 2 + (quad >> 1);
      *(ushort4v*)(&Ps[wave][l16 * 64 + (((kvblk ^ (l16 & 7)) << 3) | ((quad & 1) * 4))]) = pk;
    }

#pragma unroll
    for (int nt = 0; nt < 4; ++nt)
#pragma unroll
      for (int r = 0; r < 4; ++r) o[nt][r] *= alpha;

    // O^T += V^T · P^T ; rowsum(P) via ones-MFMA (any row of result)
    f32x4 rsv = zero;
#pragma unroll
    for (int ks = 0; ks < 2; ++ks) {
      bf16x8 pf = *(const bf16x8*)(&Ps[wave][l16 * 64 + (((ks * 4 + quad) ^ (l16 & 7)) << 3)]);
      rsv = __builtin_amdgcn_mfma_f32_16x16x32_bf16(ones, pf, rsv, 0, 0, 0);
#pragma unroll
      for (int nt = 0; nt < 4; ++nt) {
        bf16x8 vf = *(const bf16x8*)(Vb + (nt * 16 + l16) * 64 + (((ks * 4 + quad) ^ (l16 & 7)) << 3));
        o[nt] = __builtin_amdgcn_mfma_f32_16x16x32_bf16(vf, pf, o[nt], 0, 0, 0);
      }
    }
    l_i = l_i * alpha + rsv[0];
  }

  float inv = 1.f / l_i;
  int b = bh / NH_, h = bh % NH_;
#pragma unroll
  for (int nt = 0; nt < 4; ++nt) {
    ushort4v pk;
#pragma unroll
    for (int r = 0; r < 4; ++r) pk[r] = bf16rne(o[nt][r] * inv);
    int d0 = nt * 16 + quad * 4;
    *(ushort4v*)(O + ((size_t)b * S_ + qrow) * H_ + h * HD_ + d0) = pk;
  }
}

extern "C" void kernel_launch(void* const* d_in, const int* in_sizes, int n_in,
                              void* d_out, int out_size, void* d_ws, size_t ws_size,
                              hipStream_t stream) {
  (void)in_sizes; (void)n_in; (void)out_size; (void)ws_size;
  const float* hs = (const float*)d_in[0];
  const float* wqkv = (const float*)d_in[1];
  const float* wout = (const float*)d_in[2];
  float* out = (float*)d_out;

  unsigned short* Xbf = (unsigned short*)d_ws;                       // 8192*768
  unsigned short* Wqkvt = Xbf + (size_t)8192 * 768;                  // 2304*768
  unsigned short* Woutt = Wqkvt + (size_t)2304 * 768;                // 768*768
  unsigned short* QKV = Woutt + (size_t)768 * 768;                   // Q,K: 2*48*2048*64
  unsigned short* Vt = QKV + (size_t)2 * BH_ * S_ * HD_;             // 48*64*2048
  unsigned short* Attn = Xbf;  // reuse: Xbf dead after GEMM1 parts

  cvt_bf16_kernel<<<3072, 256, 0, stream>>>(hs, Xbf);
  tconv_kernel<<<dim3(36, 12), 256, 0, stream>>>(wqkv, Wqkvt, 768, 2304);
  tconv_kernel<<<dim3(12, 12), 256, 0, stream>>>(wout, Woutt, 768, 768);
  gemm_bt<0><<<dim3(64, 12), 256, 0, stream>>>(Xbf, Wqkvt, QKV, 2304, 768, 0);
  gemm_bt<2><<<dim3(64, 6), 256, 0, stream>>>(Xbf, Wqkvt, Vt, 2304, 768, 12);
  attn_kernel<<<dim3(48, 16), 512, 0, stream>>>(QKV, QKV + (size_t)BH_ * S_ * HD_, Vt, Attn);
  gemm_bt<1><<<dim3(64, 6), 256, 0, stream>>>(Attn, Woutt, out, 768, 768, 0);
}

// Round 5
// 207.015 us; speedup vs baseline: 1.7681x; 1.0879x over previous
//
#include <hip/hip_runtime.h>
#include <stdint.h>

#define B_ 4
#define S_ 2048
#define H_ 768
#define NH_ 12
#define HD_ 64
#define BH_ (B_ * NH_)  // 48

// 0.125 * log2(e): folds softmax scale AND exp->exp2 conversion into Q
#define QSCALE 0.18033688011112042f

typedef __attribute__((ext_vector_type(4))) float f32x4;
typedef __attribute__((ext_vector_type(8))) __bf16 bf16x8;
typedef __attribute__((ext_vector_type(8))) unsigned short ushort8;
typedef __attribute__((ext_vector_type(4))) unsigned short ushort4v;

__device__ __forceinline__ unsigned short bf16rne(float f) {
  union { float f; unsigned int u; } v;
  v.f = f;
  unsigned int u = v.u;
  return (unsigned short)((u + 0x7fffu + ((u >> 16) & 1u)) >> 16);
}

// packed f32x2 -> bf16x2 (RNE) — 1 instr on gfx950
#if __has_builtin(__builtin_amdgcn_cvt_pk_bf16_f32)
__device__ __forceinline__ unsigned int pk2(float a, float b) {
  auto r = __builtin_amdgcn_cvt_pk_bf16_f32(a, b);
  return *(unsigned int*)&r;
}
#else
__device__ __forceinline__ unsigned int pk2(float a, float b) {
  return (unsigned int)bf16rne(a) | ((unsigned int)bf16rne(b) << 16);
}
#endif

#if __has_builtin(__builtin_amdgcn_exp2f)
#define EXP2F(x) __builtin_amdgcn_exp2f(x)
#else
#define EXP2F(x) exp2f(x)
#endif

__device__ __forceinline__ void gll16(const void* g, void* l) {
  __builtin_amdgcn_global_load_lds(
      (const __attribute__((address_space(1))) unsigned int*)g,
      (__attribute__((address_space(3))) unsigned int*)l, 16, 0, 0);
}

// ---------------- fused prep: cvt(X) + tconv(Wqkv) + tconv(Wout) ----------------
__device__ __forceinline__ void tconv_body(const float* __restrict__ in,
                                           unsigned short* __restrict__ out,
                                           int R, int C, int bx, int by,
                                           unsigned short (*tile)[72], int tid) {
  int c0 = bx * 64, r0 = by * 64;
#pragma unroll
  for (int i = 0; i < 4; ++i) {
    int c = i * 256 + tid;
    int row = c >> 4, col4 = (c & 15) * 4;
    float4 v = *(const float4*)(in + (size_t)(r0 + row) * C + c0 + col4);
    *(uint2*)(&tile[row][col4]) = (uint2){pk2(v.x, v.y), pk2(v.z, v.w)};
  }
  __syncthreads();
#pragma unroll
  for (int i = 0; i < 2; ++i) {
    int c = i * 256 + tid;
    int oc = c >> 3, r8 = (c & 7) * 8;
    ushort8 v;
#pragma unroll
    for (int j = 0; j < 8; ++j) v[j] = tile[r8 + j][oc];
    *(ushort8*)(out + (size_t)(c0 + oc) * R + r0 + r8) = v;
  }
}

__global__ __launch_bounds__(256) void prep_kernel(const float* __restrict__ hs,
                                                   const float* __restrict__ wqkv,
                                                   const float* __restrict__ wout,
                                                   unsigned short* __restrict__ Xbf,
                                                   unsigned short* __restrict__ Wqkvt,
                                                   unsigned short* __restrict__ Woutt) {
  __shared__ unsigned short tile[64][72];
  int bid = blockIdx.x, tid = threadIdx.x;
  if (bid < 3072) {
    int i = (bid * 256 + tid) * 8;
    const float4* p = (const float4*)(hs + i);
    float4 a = p[0], b = p[1];
    uint4 r = {pk2(a.x, a.y), pk2(a.z, a.w), pk2(b.x, b.y), pk2(b.z, b.w)};
    *(uint4*)(Xbf + i) = r;
  } else if (bid < 3504) {
    int idx = bid - 3072;
    tconv_body(wqkv, Wqkvt, 768, 2304, idx % 36, idx / 36, tile, tid);
  } else {
    int idx = bid - 3504;
    tconv_body(wout, Woutt, 768, 768, idx % 12, idx / 12, tile, tid);
  }
}

// ---------------- GEMM core: 128x128 tile, A[M,K] * B'[N,K]^T (m97 structure) ----------------
// MODE 0: QK (bn<12): swapped mfma (C^T) -> r-axis = feature -> b64 stores into
//         Q [bh][s][d] (x QSCALE) and K [bh][s][d] (d-blocks XOR-swizzled by s&7).
// MODE 2: V (bn>=12): normal mfma -> r-axis = token -> b64 stores into Vt [bh][d][s]
//         (s-blocks XOR-swizzled by d&7).
// MODE 1: fp32 out: swapped mfma -> float4 stores row-major [M][N].
template <int MODE>
__device__ __forceinline__ void gemm_core(const unsigned short* __restrict__ A,
                                          const unsigned short* __restrict__ Bm,
                                          void* __restrict__ Cout, int N, int K,
                                          int bm, int bn,
                                          unsigned short* As, unsigned short* Bs) {
  int tid = threadIdx.x;
  int lane = tid & 63, wave = tid >> 6;
  int quad = lane >> 4, l16 = lane & 15;
  int wm = (wave & 1) * 64, wn = (wave >> 1) * 64;
  const unsigned short* Ag = A + (size_t)bm * 128 * K;
  const unsigned short* Bg = Bm + (size_t)bn * 128 * K;

  f32x4 zero = {0.f, 0.f, 0.f, 0.f};
  f32x4 acc[4][4];
#pragma unroll
  for (int mt = 0; mt < 4; ++mt)
#pragma unroll
    for (int nt = 0; nt < 4; ++nt) acc[mt][nt] = zero;

  for (int k0 = 0; k0 < K; k0 += 32) {
#pragma unroll
    for (int i = 0; i < 2; ++i) {
      int c = i * 256 + tid;
      int row = c >> 2, off = (c & 3) * 8;
      gll16(Ag + (size_t)row * K + k0 + off, As + c * 8);
      gll16(Bg + (size_t)row * K + k0 + off, Bs + c * 8);
    }
    __syncthreads();
    bf16x8 af[4], bf[4];
#pragma unroll
    for (int mt = 0; mt < 4; ++mt)
      af[mt] = *(const bf16x8*)(As + (wm + mt * 16 + l16) * 32 + quad * 8);
#pragma unroll
    for (int nt = 0; nt < 4; ++nt)
      bf[nt] = *(const bf16x8*)(Bs + (wn + nt * 16 + l16) * 32 + quad * 8);
#pragma unroll
    for (int mt = 0; mt < 4; ++mt)
#pragma unroll
      for (int nt = 0; nt < 4; ++nt) {
        if (MODE == 2)
          acc[mt][nt] = __builtin_amdgcn_mfma_f32_16x16x32_bf16(af[mt], bf[nt], acc[mt][nt], 0, 0, 0);
        else  // transposed: rows = features (b-side), cols = tokens (a-side)
          acc[mt][nt] = __builtin_amdgcn_mfma_f32_16x16x32_bf16(bf[nt], af[mt], acc[mt][nt], 0, 0, 0);
      }
    __syncthreads();
  }

  if (MODE == 0) {
    unsigned short* qkv = (unsigned short*)Cout;
    int which = (bn >= 6);  // block-uniform: bn 0..5 = Q, 6..11 = K
#pragma unroll
    for (int mt = 0; mt < 4; ++mt)
#pragma unroll
      for (int nt = 0; nt < 4; ++nt) {
        int f0 = bn * 128 + wn + nt * 16 + quad * 4;  // feature base (r contiguous)
        int tm = bm * 128 + wm + mt * 16 + l16;       // token
        int rem = f0 - which * 768;
        int head = rem >> 6, d0 = rem & 63;
        int b = tm >> 11, s = tm & 2047;
        if (which == 0) {
          uint2 pkv = {pk2(acc[mt][nt][0] * QSCALE, acc[mt][nt][1] * QSCALE),
                       pk2(acc[mt][nt][2] * QSCALE, acc[mt][nt][3] * QSCALE)};
          *(uint2*)(qkv + (((size_t)b * NH_ + head) * S_ + s) * HD_ + d0) = pkv;
        } else {
          uint2 pkv = {pk2(acc[mt][nt][0], acc[mt][nt][1]),
                       pk2(acc[mt][nt][2], acc[mt][nt][3])};
          int dd0 = (((d0 >> 3) ^ (s & 7)) << 3) | (d0 & 7);
          *(uint2*)(qkv + (((size_t)(BH_ + b * NH_ + head)) * S_ + s) * HD_ + dd0) = pkv;
        }
      }
  } else if (MODE == 2) {
    unsigned short* vt = (unsigned short*)Cout;
#pragma unroll
    for (int mt = 0; mt < 4; ++mt)
#pragma unroll
      for (int nt = 0; nt < 4; ++nt) {
        int f = bn * 128 + wn + nt * 16 + l16;        // feature (lane)
        int t0 = bm * 128 + wm + mt * 16 + quad * 4;  // token base (r contiguous)
        int rem = f - 1536;
        int head = rem >> 6, d = rem & 63;
        int b = t0 >> 11, s0 = t0 & 2047;
        int tile = s0 >> 6, sin = s0 & 63;
        int pos = (((sin >> 3) ^ (d & 7)) << 3) | (sin & 7);
        uint2 pkv = {pk2(acc[mt][nt][0], acc[mt][nt][1]),
                     pk2(acc[mt][nt][2], acc[mt][nt][3])};
        *(uint2*)(vt + (((size_t)(b * NH_ + head)) * HD_ + d) * S_ + tile * 64 + pos) = pkv;
      }
  } else {
    float* outp = (float*)Cout;
#pragma unroll
    for (int mt = 0; mt < 4; ++mt)
#pragma unroll
      for (int nt = 0; nt < 4; ++nt) {
        int f0 = bn * 128 + wn + nt * 16 + quad * 4;
        int tm = bm * 128 + wm + mt * 16 + l16;
        *(f32x4*)(outp + (size_t)tm * N + f0) = acc[mt][nt];
      }
  }
}

// fused QKV projection: grid (64, 18); bn<12 -> Q/K path, bn>=12 -> V path
__global__ __launch_bounds__(256) void gemm_qkv(const unsigned short* __restrict__ A,
                                                const unsigned short* __restrict__ Bm,
                                                unsigned short* __restrict__ QK,
                                                unsigned short* __restrict__ Vt) {
  __shared__ unsigned short As[128 * 32];
  __shared__ unsigned short Bs[128 * 32];
  int bm = blockIdx.x, bn = blockIdx.y;
  if (bn < 12)
    gemm_core<0>(A, Bm, QK, 2304, 768, bm, bn, As, Bs);
  else
    gemm_core<2>(A, Bm, Vt, 2304, 768, bm, bn, As, Bs);
}

__global__ __launch_bounds__(256) void gemm_out(const unsigned short* __restrict__ A,
                                                const unsigned short* __restrict__ Bm,
                                                float* __restrict__ Cout) {
  __shared__ unsigned short As[128 * 32];
  __shared__ unsigned short Bs[128 * 32];
  gemm_core<1>(A, Bm, Cout, 768, 768, blockIdx.x, blockIdx.y, As, Bs);
}

// ---------------- Flash attention, causal, S^T formulation, exp2 domain ----------------
// grid (48, 16): 512 threads, Q-tile 128 (8 waves x 16 q), KV tiles 64, dbuf K/V.
// S^T = K·Q  => softmax state is per-lane scalar (q = l16 column).
// Q pre-scaled by 0.125*log2(e) => softmax uses raw v_exp_f32 (exp2).
// P^T->LDS via ds_write_b64 (HW packed bf16 cvt); O^T = V^T·P^T => packed b64 O stores.
__global__ __launch_bounds__(512, 6) void attn_kernel(const unsigned short* __restrict__ Q,
                                                      const unsigned short* __restrict__ Kg,
                                                      const unsigned short* __restrict__ Vt,
                                                      unsigned short* __restrict__ O) {
  __shared__ unsigned short Ks[2][64 * 64];
  __shared__ unsigned short Vs[2][64 * 64];
  __shared__ unsigned short Ps[8][16 * 64];
  int bh = blockIdx.x;
  int y = blockIdx.y;
  int qt = (y & 1) ? (15 - (y >> 1)) : (y >> 1);
  int tid = threadIdx.x, lane = tid & 63, wave = tid >> 6;
  int quad = lane >> 4, l16 = lane & 15;
  const unsigned short* Qp = Q + (size_t)bh * S_ * HD_;
  const unsigned short* Kp = Kg + (size_t)bh * S_ * HD_;
  const unsigned short* Vp = Vt + (size_t)bh * HD_ * S_;
  int q0 = qt * 128;
  int qrow = q0 + wave * 16 + l16;                 // this lane's q (S^T column)
  int kmax_w = (q0 + wave * 16 + 15) >> 6;         // last kv-tile this wave needs
  int kmax_b = 2 * qt + 1;                         // last kv-tile this block stages

  auto stage = [&](int t, int buf) {               // 512 thr: 1 gll16 each for K and V
    int row = tid >> 3, off = (tid & 7) * 8;
    gll16(Kp + (size_t)t * 64 * HD_ + row * HD_ + off, &Ks[buf][tid * 8]);
    gll16(Vp + (size_t)row * S_ + t * 64 + off, &Vs[buf][tid * 8]);
  };

  stage(0, 0);  // Q-frag loads below overlap the first staging

  bf16x8 qf[2];
#pragma unroll
  for (int ks = 0; ks < 2; ++ks)
    qf[ks] = *(const bf16x8*)(Qp + (size_t)qrow * HD_ + ks * 32 + quad * 8);

  bf16x8 ones;
#pragma unroll
  for (int j = 0; j < 8; ++j) ones[j] = (__bf16)1.0f;

  f32x4 zero = {0.f, 0.f, 0.f, 0.f};
  float m_i = -1e30f, l_i = 0.f;
  f32x4 o[4];
#pragma unroll
  for (int nt = 0; nt < 4; ++nt) o[nt] = zero;

  for (int t = 0; t <= kmax_b; ++t) {
    __syncthreads();                       // drains prefetch(t) + guards buffer reuse
    if (t < kmax_b) stage(t + 1, (t + 1) & 1);
    if (t > kmax_w) continue;              // fully-masked tile for this wave
    const unsigned short* Kb = Ks[t & 1];
    const unsigned short* Vb = Vs[t & 1];

    // S^T = K·Q : rows kv (quad*4+r per nt-block), cols q (l16)
    f32x4 sf[4];
#pragma unroll
    for (int nt = 0; nt < 4; ++nt) sf[nt] = zero;
#pragma unroll
    for (int ks = 0; ks < 2; ++ks)
#pragma unroll
      for (int nt = 0; nt < 4; ++nt) {
        bf16x8 kf = *(const bf16x8*)(Kb + (nt * 16 + l16) * 64 + (((ks * 4 + quad) ^ (l16 & 7)) << 3));
        sf[nt] = __builtin_amdgcn_mfma_f32_16x16x32_bf16(kf, qf[ks], sf[nt], 0, 0, 0);
      }

    if (t == kmax_w) {  // causal boundary tile: mask kv > q
#pragma unroll
      for (int nt = 0; nt < 4; ++nt)
#pragma unroll
        for (int r = 0; r < 4; ++r)
          if (t * 64 + nt * 16 + quad * 4 + r > qrow) sf[nt][r] = -1e30f;
    }

    // per-lane scalar online softmax (column q = l16), log2 domain
    float mx = fmaxf(fmaxf(fmaxf(sf[0][0], sf[0][1]), fmaxf(sf[0][2], sf[0][3])),
                     fmaxf(fmaxf(sf[1][0], sf[1][1]), fmaxf(sf[1][2], sf[1][3])));
    mx = fmaxf(mx, fmaxf(fmaxf(fmaxf(sf[2][0], sf[2][1]), fmaxf(sf[2][2], sf[2][3])),
                         fmaxf(fmaxf(sf[3][0], sf[3][1]), fmaxf(sf[3][2], sf[3][3]))));
    mx = fmaxf(mx, __shfl_xor(mx, 16));
    mx = fmaxf(mx, __shfl_xor(mx, 32));
    float mn = fmaxf(m_i, mx);
    float alpha = EXP2F(m_i - mn);
    m_i = mn;

    // P^T -> Ps[q][kv], XOR-swizzled 8-blocks, packed-cvt + b64 writes
#pragma unroll
    for (int nt = 0; nt < 4; ++nt) {
      uint2 pkv = {pk2(EXP2F(sf[nt][0] - mn), EXP2F(sf[nt][1] - mn)),
                   pk2(EXP2F(sf[nt][2] - mn), EXP2F(sf[nt][3] - mn))};
      int kvblk = nt * 2 + (quad >> 1);
      *(uint2*)(&Ps[wave][l16 * 64 + (((kvblk ^ (l16 & 7)) << 3) | ((quad & 1) * 4))]) = pkv;
    }

#pragma unroll
    for (int nt = 0; nt < 4; ++nt)
#pragma unroll
      for (int r = 0; r < 4; ++r) o[nt][r] *= alpha;

    // O^T += V^T · P^T ; rowsum(P) via ones-MFMA (any row of result)
    f32x4 rsv = zero;
#pragma unroll
    for (int ks = 0; ks < 2; ++ks) {
      bf16x8 pf = *(const bf16x8*)(&Ps[wave][l16 * 64 + (((ks * 4 + quad) ^ (l16 & 7)) << 3)]);
      rsv = __builtin_amdgcn_mfma_f32_16x16x32_bf16(ones, pf, rsv, 0, 0, 0);
#pragma unroll
      for (int nt = 0; nt < 4; ++nt) {
        bf16x8 vf = *(const bf16x8*)(Vb + (nt * 16 + l16) * 64 + (((ks * 4 + quad) ^ (l16 & 7)) << 3));
        o[nt] = __builtin_amdgcn_mfma_f32_16x16x32_bf16(vf, pf, o[nt], 0, 0, 0);
      }
    }
    l_i = l_i * alpha + rsv[0];
  }

  float inv = 1.f / l_i;
  int b = bh / NH_, h = bh % NH_;
#pragma unroll
  for (int nt = 0; nt < 4; ++nt) {
    uint2 pkv = {pk2(o[nt][0] * inv, o[nt][1] * inv),
                 pk2(o[nt][2] * inv, o[nt][3] * inv)};
    int d0 = nt * 16 + quad * 4;
    *(uint2*)(O + ((size_t)b * S_ + qrow) * H_ + h * HD_ + d0) = pkv;
  }
}

extern "C" void kernel_launch(void* const* d_in, const int* in_sizes, int n_in,
                              void* d_out, int out_size, void* d_ws, size_t ws_size,
                              hipStream_t stream) {
  (void)in_sizes; (void)n_in; (void)out_size; (void)ws_size;
  const float* hs = (const float*)d_in[0];
  const float* wqkv = (const float*)d_in[1];
  const float* wout = (const float*)d_in[2];
  float* out = (float*)d_out;

  unsigned short* Xbf = (unsigned short*)d_ws;                       // 8192*768
  unsigned short* Wqkvt = Xbf + (size_t)8192 * 768;                  // 2304*768
  unsigned short* Woutt = Wqkvt + (size_t)2304 * 768;                // 768*768
  unsigned short* QK = Woutt + (size_t)768 * 768;                    // Q,K: 2*48*2048*64
  unsigned short* Vt = QK + (size_t)2 * BH_ * S_ * HD_;              // 48*64*2048
  unsigned short* Attn = Xbf;  // reuse: Xbf dead after gemm_qkv

  prep_kernel<<<3648, 256, 0, stream>>>(hs, wqkv, wout, Xbf, Wqkvt, Woutt);
  gemm_qkv<<<dim3(64, 18), 256, 0, stream>>>(Xbf, Wqkvt, QK, Vt);
  attn_kernel<<<dim3(48, 16), 512, 0, stream>>>(QK, QK + (size_t)BH_ * S_ * HD_, Vt, Attn);
  gemm_out<<<dim3(64, 6), 256, 0, stream>>>(Attn, Woutt, out);
}